// Round 1
// baseline (475.389 us; speedup 1.0000x reference)
//
#include <hip/hip_runtime.h>
#include <hip/hip_bf16.h>
#include <cstdint>
#include <cstddef>

// ---- types ----
typedef __bf16 bf16_t;
typedef __bf16 bf16x8 __attribute__((ext_vector_type(8)));
typedef float f32x4 __attribute__((ext_vector_type(4)));

static __device__ __forceinline__ void st_out(float* p, float v) { *p = v; }
static __device__ __forceinline__ void st_out(bf16_t* p, float v) { *p = (bf16_t)v; }

// =====================================================================
// fp32 -> bf16 bulk cast (8 elems/thread)
// =====================================================================
__global__ __launch_bounds__(256) void cvt_f32_bf16(const float* __restrict__ s,
                                                    bf16_t* __restrict__ d, int n) {
  int i = (blockIdx.x * 256 + threadIdx.x) * 8;
  if (i >= n) return;
  float4 a = *(const float4*)(s + i);
  float4 b = *(const float4*)(s + i + 4);
  union { bf16_t h[8]; uint4 u; } p;
  p.h[0] = (bf16_t)a.x; p.h[1] = (bf16_t)a.y; p.h[2] = (bf16_t)a.z; p.h[3] = (bf16_t)a.w;
  p.h[4] = (bf16_t)b.x; p.h[5] = (bf16_t)b.y; p.h[6] = (bf16_t)b.z; p.h[7] = (bf16_t)b.w;
  *(uint4*)(d + i) = p.u;
}

// =====================================================================
// fp32 [R][C] -> bf16 [C][R] tiled transpose (R,C multiples of 32)
// =====================================================================
__global__ __launch_bounds__(256) void transpose_f32_bf16(const float* __restrict__ src,
                                                          bf16_t* __restrict__ dst,
                                                          int R, int C) {
  __shared__ float tile[32][33];
  int bx = blockIdx.x * 32, by = blockIdx.y * 32;
  int tx = threadIdx.x, ty = threadIdx.y;
#pragma unroll
  for (int i = 0; i < 4; ++i)
    tile[ty + i * 8][tx] = src[(size_t)(by + ty + i * 8) * C + bx + tx];
  __syncthreads();
#pragma unroll
  for (int i = 0; i < 4; ++i)
    dst[(size_t)(bx + ty + i * 8) * R + by + tx] = (bf16_t)tile[tx][ty + i * 8];
}

// =====================================================================
// concat bq|bk|bv -> bias3[3072]
// =====================================================================
__global__ __launch_bounds__(256) void concat_bias(const float* __restrict__ b0,
                                                   const float* __restrict__ b1,
                                                   const float* __restrict__ b2,
                                                   float* __restrict__ dst) {
  int i = blockIdx.x * 256 + threadIdx.x;
  dst[i] = (i < 1024) ? b0[i] : (i < 2048 ? b1[i - 1024] : b2[i - 2048]);
}

// =====================================================================
// C[M,N] = A[M,K] * Bt[N,K]^T + bias ; 128x128 tile, 4 waves (2x2), each 64x64
// MFMA 16x16x32 bf16. LDS rows padded to 40 elems (80 B stride: 16B-aligned,
// 2-way bank aliasing only -> free per m136).
// =====================================================================
template <typename OutT>
__global__ __launch_bounds__(256) void gemm_bt(const bf16_t* __restrict__ A, int lda,
                                               const bf16_t* __restrict__ Bt, int ldb,
                                               OutT* __restrict__ C, int ldc,
                                               const float* __restrict__ bias, int K) {
  __shared__ bf16_t As[128][40];
  __shared__ bf16_t Bs[128][40];
  const int m0 = blockIdx.y * 128, n0 = blockIdx.x * 128;
  const int t = threadIdx.x, w = t >> 6, lane = t & 63;
  const int wm = (w >> 1) * 64, wn = (w & 1) * 64;
  const int quad = lane >> 4, l16 = lane & 15;
  const int sr = t >> 1, sc = (t & 1) << 4;

  f32x4 acc[4][4] = {};
  const bf16_t* Ag = A + (size_t)(m0 + sr) * lda + sc;
  const bf16_t* Bg = Bt + (size_t)(n0 + sr) * ldb + sc;

  for (int k0 = 0; k0 < K; k0 += 32) {
    __syncthreads();
    float4 a0 = *(const float4*)(Ag + k0);
    float4 a1 = *(const float4*)(Ag + k0 + 8);
    float4 b0 = *(const float4*)(Bg + k0);
    float4 b1 = *(const float4*)(Bg + k0 + 8);
    *(float4*)&As[sr][sc]     = a0;
    *(float4*)&As[sr][sc + 8] = a1;
    *(float4*)&Bs[sr][sc]     = b0;
    *(float4*)&Bs[sr][sc + 8] = b1;
    __syncthreads();
    bf16x8 af[4], bfr[4];
#pragma unroll
    for (int i = 0; i < 4; ++i)
      af[i] = *(const bf16x8*)&As[wm + i * 16 + l16][quad * 8];
#pragma unroll
    for (int j = 0; j < 4; ++j)
      bfr[j] = *(const bf16x8*)&Bs[wn + j * 16 + l16][quad * 8];
#pragma unroll
    for (int i = 0; i < 4; ++i)
#pragma unroll
      for (int j = 0; j < 4; ++j)
        acc[i][j] = __builtin_amdgcn_mfma_f32_16x16x32_bf16(af[i], bfr[j], acc[i][j], 0, 0, 0);
  }
#pragma unroll
  for (int i = 0; i < 4; ++i) {
    int row = m0 + wm + i * 16 + quad * 4;
#pragma unroll
    for (int j = 0; j < 4; ++j) {
      int col = n0 + wn + j * 16 + l16;
      float bv = bias ? bias[col] : 0.f;
#pragma unroll
      for (int r = 0; r < 4; ++r)
        st_out(&C[(size_t)(row + r) * ldc + col], acc[i][j][r] + bv);
    }
  }
}

// =====================================================================
// lin = Low[:, off:off+64] @ TbT^T (K=64), then in-place
// X += sigmoid(c) * sin(phase_mult*lin)*lin*inv_np1  (one torsion order)
// =====================================================================
__global__ __launch_bounds__(256) void lin_torsion(const bf16_t* __restrict__ Low, // + col offset, lda=128
                                                   const bf16_t* __restrict__ TbT, // [1024][64]
                                                   bf16_t* __restrict__ X, int ldx,
                                                   const float* __restrict__ coupling,
                                                   float phase_mult, float inv_np1) {
  __shared__ bf16_t As[128][72];
  __shared__ bf16_t Bs[128][72];
  const int m0 = blockIdx.y * 128, n0 = blockIdx.x * 128;
  const int t = threadIdx.x, w = t >> 6, lane = t & 63;
  const int wm = (w >> 1) * 64, wn = (w & 1) * 64;
  const int quad = lane >> 4, l16 = lane & 15;
  const int sr = t >> 1, sc = (t & 1) * 32;

  {
    const bf16_t* Ag = Low + (size_t)(m0 + sr) * 128 + sc;
    const bf16_t* Bg = TbT + (size_t)(n0 + sr) * 64 + sc;
#pragma unroll
    for (int i = 0; i < 4; ++i) {
      *(float4*)&As[sr][sc + 8 * i] = *(const float4*)(Ag + 8 * i);
      *(float4*)&Bs[sr][sc + 8 * i] = *(const float4*)(Bg + 8 * i);
    }
  }
  __syncthreads();

  f32x4 acc[4][4] = {};
#pragma unroll
  for (int ks = 0; ks < 2; ++ks) {
    bf16x8 af[4];
#pragma unroll
    for (int i = 0; i < 4; ++i)
      af[i] = *(const bf16x8*)&As[wm + i * 16 + l16][ks * 32 + quad * 8];
#pragma unroll
    for (int j = 0; j < 4; ++j) {
      bf16x8 bfr = *(const bf16x8*)&Bs[wn + j * 16 + l16][ks * 32 + quad * 8];
#pragma unroll
      for (int i = 0; i < 4; ++i)
        acc[i][j] = __builtin_amdgcn_mfma_f32_16x16x32_bf16(af[i], bfr, acc[i][j], 0, 0, 0);
    }
  }

  const float sig = 1.f / (1.f + __expf(-coupling[0]));
#pragma unroll
  for (int i = 0; i < 4; ++i) {
#pragma unroll
    for (int j = 0; j < 4; ++j) {
#pragma unroll
      for (int r = 0; r < 4; ++r) {
        int row = m0 + wm + i * 16 + quad * 4 + r;
        int col = n0 + wn + j * 16 + l16;
        size_t idx = (size_t)row * ldx + col;
        float l = acc[i][j][r];
        float corr = sinf(phase_mult * l) * l * inv_np1;
        X[idx] = (bf16_t)((float)X[idx] + sig * corr);
      }
    }
  }
}

// =====================================================================
// Flash attention: B=2, S=2048, NH=16, HD=64, qkv packed [4096][3072].
// BM=128 queries/block (4 waves x 32 rows), BN=128 keys/iter, online softmax.
// LDS: Ps[128][136] (overlays Qs) + Ks[128][72] (overlaid by VTs[64][136]
// after QK) = 53 KB.
// =====================================================================
__global__ __launch_bounds__(256) void flash_attn(const bf16_t* __restrict__ qkv,
                                                  bf16_t* __restrict__ Out) {
  constexpr int LD = 3072, SEQ = 2048, LDO = 1024;
  const int qb = blockIdx.x, bh = blockIdx.y;
  const int b = bh >> 4, h = bh & 15;
  const size_t base = (size_t)b * SEQ * LD + h * 64;
  const bf16_t* Qg = qkv + base;
  const bf16_t* Kg = qkv + base + 1024;
  const bf16_t* Vg = qkv + base + 2048;

  __shared__ __align__(16) unsigned char smem[34816 + 18432];
  bf16_t(*Ps)[136] = (bf16_t(*)[136])smem;            // [128][136]
  bf16_t(*Qs)[72] = (bf16_t(*)[72])smem;              // init only, overlaid by Ps
  bf16_t(*Ks)[72] = (bf16_t(*)[72])(smem + 34816);    // [128][72]
  bf16_t(*VTs)[136] = (bf16_t(*)[136])(smem + 34816); // [64][136], overlays Ks after QK

  const int t = threadIdx.x, w = t >> 6, lane = t & 63;
  const int quad = lane >> 4, l16 = lane & 15;
  const int sr = t >> 1, scb = (t & 1) * 32;
  const int q0 = qb * 128;

  {
    const bf16_t* src = Qg + (size_t)(q0 + sr) * LD + scb;
#pragma unroll
    for (int i = 0; i < 4; ++i)
      *(float4*)&Qs[sr][scb + 8 * i] = *(const float4*)(src + 8 * i);
  }
  __syncthreads();
  bf16x8 qf[2][2];
#pragma unroll
  for (int mt = 0; mt < 2; ++mt)
#pragma unroll
    for (int ks = 0; ks < 2; ++ks)
      qf[mt][ks] = *(const bf16x8*)&Qs[w * 32 + mt * 16 + l16][ks * 32 + quad * 8];

  f32x4 o_acc[2][4] = {};
  float m_i[2][4], l_i[2][4];
#pragma unroll
  for (int mt = 0; mt < 2; ++mt)
#pragma unroll
    for (int r = 0; r < 4; ++r) { m_i[mt][r] = -1e30f; l_i[mt][r] = 0.f; }

  for (int k0 = 0; k0 < SEQ; k0 += 128) {
    __syncthreads(); // prev-iter PV reads of Ps/VTs done
    float4 vreg[4];
    {
      const bf16_t* ksrc = Kg + (size_t)(k0 + sr) * LD + scb;
      const bf16_t* vsrc = Vg + (size_t)(k0 + sr) * LD + scb;
#pragma unroll
      for (int i = 0; i < 4; ++i) {
        *(float4*)&Ks[sr][scb + 8 * i] = *(const float4*)(ksrc + 8 * i);
        vreg[i] = *(const float4*)(vsrc + 8 * i);
      }
    }
    __syncthreads(); // Ks ready

    f32x4 s[2][8] = {};
#pragma unroll
    for (int ks = 0; ks < 2; ++ks) {
#pragma unroll
      for (int j = 0; j < 8; ++j) {
        bf16x8 kf = *(const bf16x8*)&Ks[j * 16 + l16][ks * 32 + quad * 8];
        s[0][j] = __builtin_amdgcn_mfma_f32_16x16x32_bf16(qf[0][ks], kf, s[0][j], 0, 0, 0);
        s[1][j] = __builtin_amdgcn_mfma_f32_16x16x32_bf16(qf[1][ks], kf, s[1][j], 0, 0, 0);
      }
    }

#pragma unroll
    for (int mt = 0; mt < 2; ++mt) {
#pragma unroll
      for (int r = 0; r < 4; ++r) {
        float rowmax = -1e30f;
#pragma unroll
        for (int j = 0; j < 8; ++j) {
          s[mt][j][r] *= 0.125f; // 1/sqrt(64)
          rowmax = fmaxf(rowmax, s[mt][j][r]);
        }
#pragma unroll
        for (int d = 1; d < 16; d <<= 1)
          rowmax = fmaxf(rowmax, __shfl_xor(rowmax, d));
        float mnew = fmaxf(m_i[mt][r], rowmax);
        float alpha = __expf(m_i[mt][r] - mnew);
        float rs = 0.f;
#pragma unroll
        for (int j = 0; j < 8; ++j) {
          float p = __expf(s[mt][j][r] - mnew);
          s[mt][j][r] = p;
          rs += p;
        }
#pragma unroll
        for (int d = 1; d < 16; d <<= 1) rs += __shfl_xor(rs, d);
        m_i[mt][r] = mnew;
        l_i[mt][r] = l_i[mt][r] * alpha + rs;
#pragma unroll
        for (int jd = 0; jd < 4; ++jd) o_acc[mt][jd][r] *= alpha;
      }
    }

    // P -> LDS (wave-local rows: no barrier needed for Ps itself)
#pragma unroll
    for (int mt = 0; mt < 2; ++mt)
#pragma unroll
      for (int j = 0; j < 8; ++j)
#pragma unroll
        for (int r = 0; r < 4; ++r)
          Ps[w * 32 + mt * 16 + quad * 4 + r][j * 16 + l16] = (bf16_t)s[mt][j][r];

    __syncthreads(); // all QK reads of Ks done -> safe to overlay with VT
    {
#pragma unroll
      for (int i = 0; i < 4; ++i) {
        union { float4 f; bf16_t hh[8]; } u;
        u.f = vreg[i];
#pragma unroll
        for (int e = 0; e < 8; ++e) VTs[scb + 8 * i + e][sr] = u.hh[e];
      }
    }
    __syncthreads(); // VT ready

#pragma unroll
    for (int ks = 0; ks < 4; ++ks) {
      bf16x8 pa0 = *(const bf16x8*)&Ps[w * 32 + l16][ks * 32 + quad * 8];
      bf16x8 pa1 = *(const bf16x8*)&Ps[w * 32 + 16 + l16][ks * 32 + quad * 8];
#pragma unroll
      for (int jd = 0; jd < 4; ++jd) {
        bf16x8 vf = *(const bf16x8*)&VTs[jd * 16 + l16][ks * 32 + quad * 8];
        o_acc[0][jd] = __builtin_amdgcn_mfma_f32_16x16x32_bf16(pa0, vf, o_acc[0][jd], 0, 0, 0);
        o_acc[1][jd] = __builtin_amdgcn_mfma_f32_16x16x32_bf16(pa1, vf, o_acc[1][jd], 0, 0, 0);
      }
    }
  }

#pragma unroll
  for (int mt = 0; mt < 2; ++mt)
#pragma unroll
    for (int jd = 0; jd < 4; ++jd)
#pragma unroll
      for (int r = 0; r < 4; ++r) {
        int row = q0 + w * 32 + mt * 16 + quad * 4 + r;
        int col = h * 64 + jd * 16 + l16;
        Out[(size_t)(b * SEQ + row) * LDO + col] = (bf16_t)(o_acc[mt][jd][r] / l_i[mt][r]);
      }
}

// =====================================================================
// host launch
// =====================================================================
extern "C" void kernel_launch(void* const* d_in, const int* in_sizes, int n_in,
                              void* d_out, int out_size, void* d_ws, size_t ws_size,
                              hipStream_t stream) {
  const float* hs   = (const float*)d_in[0];
  const float* Wq   = (const float*)d_in[1];
  const float* bq   = (const float*)d_in[2];
  const float* Wk   = (const float*)d_in[3];
  const float* bk   = (const float*)d_in[4];
  const float* Wv   = (const float*)d_in[5];
  const float* bv   = (const float*)d_in[6];
  const float* Wo   = (const float*)d_in[7];
  const float* bo   = (const float*)d_in[8];
  const float* qta  = (const float*)d_in[9];
  const float* qtb  = (const float*)d_in[10];
  const float* kta  = (const float*)d_in[11];
  const float* ktb  = (const float*)d_in[12];
  const float* coup = (const float*)d_in[13];
  float* out = (float*)d_out;

  uint8_t* ws = (uint8_t*)d_ws;
  bf16_t* hsb   = (bf16_t*)(ws);
  bf16_t* WT    = (bf16_t*)(ws + 8388608);   // [3072][1024]
  bf16_t* WoT   = (bf16_t*)(ws + 14680064);  // [1024][1024]
  bf16_t* qtaT  = (bf16_t*)(ws + 16777216);  // [128][1024]
  bf16_t* ktaT  = (bf16_t*)(ws + 17039360);
  bf16_t* qtbT  = (bf16_t*)(ws + 17301504);  // [2][1024][64]
  bf16_t* ktbT  = (bf16_t*)(ws + 17563648);
  float*  bias3 = (float*)(ws + 17825792);   // [3072]
  bf16_t* qkv   = (bf16_t*)(ws + 17838080);  // [4096][3072]
  bf16_t* lowq  = (bf16_t*)(ws + 43003904);  // [4096][128]
  bf16_t* lowk  = (bf16_t*)(ws + 44052480);
  bf16_t* aout  = (bf16_t*)(ws + 45101056);  // [4096][1024]

  dim3 b256(256);
  dim3 tb(32, 8);
  const float PI2 = 6.283185307179586f;

  cvt_f32_bf16<<<2048, b256, 0, stream>>>(hs, hsb, 4194304);
  transpose_f32_bf16<<<dim3(32, 32), tb, 0, stream>>>(Wq, WT,           1024, 1024);
  transpose_f32_bf16<<<dim3(32, 32), tb, 0, stream>>>(Wk, WT + 1048576, 1024, 1024);
  transpose_f32_bf16<<<dim3(32, 32), tb, 0, stream>>>(Wv, WT + 2097152, 1024, 1024);
  transpose_f32_bf16<<<dim3(32, 32), tb, 0, stream>>>(Wo, WoT,          1024, 1024);
  transpose_f32_bf16<<<dim3(2, 32), tb, 0, stream>>>(qta,         qtaT,         1024, 64);
  transpose_f32_bf16<<<dim3(2, 32), tb, 0, stream>>>(qta + 65536, qtaT + 65536, 1024, 64);
  transpose_f32_bf16<<<dim3(2, 32), tb, 0, stream>>>(kta,         ktaT,         1024, 64);
  transpose_f32_bf16<<<dim3(2, 32), tb, 0, stream>>>(kta + 65536, ktaT + 65536, 1024, 64);
  transpose_f32_bf16<<<dim3(32, 2), tb, 0, stream>>>(qtb,         qtbT,         64, 1024);
  transpose_f32_bf16<<<dim3(32, 2), tb, 0, stream>>>(qtb + 65536, qtbT + 65536, 64, 1024);
  transpose_f32_bf16<<<dim3(32, 2), tb, 0, stream>>>(ktb,         ktbT,         64, 1024);
  transpose_f32_bf16<<<dim3(32, 2), tb, 0, stream>>>(ktb + 65536, ktbT + 65536, 64, 1024);
  concat_bias<<<12, b256, 0, stream>>>(bq, bk, bv, bias3);

  // QKV projection: [4096,1024] x [1024,3072] + bias
  gemm_bt<bf16_t><<<dim3(24, 32), b256, 0, stream>>>(hsb, 1024, WT, 1024, qkv, 3072, bias3, 1024);
  // torsion low-rank: low = x @ ta  (both orders concatenated along N=128)
  gemm_bt<bf16_t><<<dim3(1, 32), b256, 0, stream>>>(qkv,        3072, qtaT, 1024, lowq, 128, nullptr, 1024);
  gemm_bt<bf16_t><<<dim3(1, 32), b256, 0, stream>>>(qkv + 1024, 3072, ktaT, 1024, lowk, 128, nullptr, 1024);
  // torsion lin + in-place correction, per order
  lin_torsion<<<dim3(8, 32), b256, 0, stream>>>(lowq,      qtbT,         qkv,        3072, coup, PI2,       1.0f);
  lin_torsion<<<dim3(8, 32), b256, 0, stream>>>(lowq + 64, qtbT + 65536, qkv,        3072, coup, 2.f * PI2, 0.5f);
  lin_torsion<<<dim3(8, 32), b256, 0, stream>>>(lowk,      ktbT,         qkv + 1024, 3072, coup, PI2,       1.0f);
  lin_torsion<<<dim3(8, 32), b256, 0, stream>>>(lowk + 64, ktbT + 65536, qkv + 1024, 3072, coup, 2.f * PI2, 0.5f);
  // attention
  flash_attn<<<dim3(16, 32), b256, 0, stream>>>(qkv, aout);
  // output projection (fp32 out)
  gemm_bt<float><<<dim3(8, 32), b256, 0, stream>>>(aout, 1024, WoT, 1024, out, 1024, bo, 1024);
}

// Round 2
// 358.788 us; speedup vs baseline: 1.3250x; 1.3250x over previous
//
#include <hip/hip_runtime.h>
#include <hip/hip_bf16.h>
#include <cstdint>
#include <cstddef>

typedef __bf16 bf16_t;
typedef __bf16 bf16x8 __attribute__((ext_vector_type(8)));
typedef float f32x4 __attribute__((ext_vector_type(4)));

static __device__ __forceinline__ void st_out(float* p, float v) { *p = v; }
static __device__ __forceinline__ void st_out(bf16_t* p, float v) { *p = (bf16_t)v; }

// =====================================================================
// fp32 -> bf16 bulk cast (8 elems/thread)
// =====================================================================
__global__ __launch_bounds__(256) void cvt_f32_bf16(const float* __restrict__ s,
                                                    bf16_t* __restrict__ d, int n) {
  int i = (blockIdx.x * 256 + threadIdx.x) * 8;
  if (i >= n) return;
  float4 a = *(const float4*)(s + i);
  float4 b = *(const float4*)(s + i + 4);
  union { bf16_t h[8]; uint4 u; } p;
  p.h[0] = (bf16_t)a.x; p.h[1] = (bf16_t)a.y; p.h[2] = (bf16_t)a.z; p.h[3] = (bf16_t)a.w;
  p.h[4] = (bf16_t)b.x; p.h[5] = (bf16_t)b.y; p.h[6] = (bf16_t)b.z; p.h[7] = (bf16_t)b.w;
  *(uint4*)(d + i) = p.u;
}

// =====================================================================
// batched fp32 [R][C] -> bf16 [C][R] transpose. grid.z = 4 slices:
// tensor = z>>1 (a/b), order = z&1 (offset order*R*C on both sides)
// =====================================================================
__global__ __launch_bounds__(256) void transpose_batch(const float* __restrict__ a,
                                                       const float* __restrict__ b,
                                                       bf16_t* __restrict__ da,
                                                       bf16_t* __restrict__ db,
                                                       int R, int C) {
  __shared__ float tile[32][33];
  int z = blockIdx.z;
  const float* src = (z >> 1 ? b : a) + (size_t)(z & 1) * R * C;
  bf16_t* dst = (z >> 1 ? db : da) + (size_t)(z & 1) * R * C;
  int bx = blockIdx.x * 32, by = blockIdx.y * 32;
  int tx = threadIdx.x, ty = threadIdx.y;
#pragma unroll
  for (int i = 0; i < 4; ++i)
    tile[ty + i * 8][tx] = src[(size_t)(by + ty + i * 8) * C + bx + tx];
  __syncthreads();
#pragma unroll
  for (int i = 0; i < 4; ++i)
    dst[(size_t)(bx + ty + i * 8) * R + by + tx] = (bf16_t)tile[tx][ty + i * 8];
}

// 4 independent 1024x1024 weight transposes in one launch (grid.z picks)
__global__ __launch_bounds__(256) void transpose4(const float* __restrict__ p0,
                                                  const float* __restrict__ p1,
                                                  const float* __restrict__ p2,
                                                  const float* __restrict__ p3,
                                                  bf16_t* __restrict__ d0,
                                                  bf16_t* __restrict__ d1,
                                                  bf16_t* __restrict__ d2,
                                                  bf16_t* __restrict__ d3) {
  __shared__ float tile[32][33];
  int z = blockIdx.z;
  const float* src = z == 0 ? p0 : z == 1 ? p1 : z == 2 ? p2 : p3;
  bf16_t* dst = z == 0 ? d0 : z == 1 ? d1 : z == 2 ? d2 : d3;
  int bx = blockIdx.x * 32, by = blockIdx.y * 32;
  int tx = threadIdx.x, ty = threadIdx.y;
#pragma unroll
  for (int i = 0; i < 4; ++i)
    tile[ty + i * 8][tx] = src[(size_t)(by + ty + i * 8) * 1024 + bx + tx];
  __syncthreads();
#pragma unroll
  for (int i = 0; i < 4; ++i)
    dst[(size_t)(bx + ty + i * 8) * 1024 + by + tx] = (bf16_t)tile[tx][ty + i * 8];
}

// =====================================================================
// core GEMM: C[M,N] = A[M,K] * Bt[N,K]^T + bias(col-select b0/b1/b2)
// 128x128 tile, 4 waves (2x2) of 64x64, MFMA 16x16x32 bf16.
// =====================================================================
template <typename OutT>
static __device__ __forceinline__ void gemm_core(const bf16_t* __restrict__ A, int lda,
                                                 const bf16_t* __restrict__ Bt, int ldb,
                                                 OutT* __restrict__ C, int ldc,
                                                 const float* b0, const float* b1,
                                                 const float* b2, int K,
                                                 int bx, int by) {
  __shared__ bf16_t As[128][40];
  __shared__ bf16_t Bs[128][40];
  const int m0 = by * 128, n0 = bx * 128;
  const int t = threadIdx.x, w = t >> 6, lane = t & 63;
  const int wm = (w >> 1) * 64, wn = (w & 1) * 64;
  const int quad = lane >> 4, l16 = lane & 15;
  const int sr = t >> 1, sc = (t & 1) << 4;

  f32x4 acc[4][4] = {};
  const bf16_t* Ag = A + (size_t)(m0 + sr) * lda + sc;
  const bf16_t* Bg = Bt + (size_t)(n0 + sr) * ldb + sc;

  for (int k0 = 0; k0 < K; k0 += 32) {
    __syncthreads();
    float4 a0 = *(const float4*)(Ag + k0);
    float4 a1 = *(const float4*)(Ag + k0 + 8);
    float4 b0v = *(const float4*)(Bg + k0);
    float4 b1v = *(const float4*)(Bg + k0 + 8);
    *(float4*)&As[sr][sc]     = a0;
    *(float4*)&As[sr][sc + 8] = a1;
    *(float4*)&Bs[sr][sc]     = b0v;
    *(float4*)&Bs[sr][sc + 8] = b1v;
    __syncthreads();
    bf16x8 af[4], bfr[4];
#pragma unroll
    for (int i = 0; i < 4; ++i)
      af[i] = *(const bf16x8*)&As[wm + i * 16 + l16][quad * 8];
#pragma unroll
    for (int j = 0; j < 4; ++j)
      bfr[j] = *(const bf16x8*)&Bs[wn + j * 16 + l16][quad * 8];
#pragma unroll
    for (int i = 0; i < 4; ++i)
#pragma unroll
      for (int j = 0; j < 4; ++j)
        acc[i][j] = __builtin_amdgcn_mfma_f32_16x16x32_bf16(af[i], bfr[j], acc[i][j], 0, 0, 0);
  }
#pragma unroll
  for (int i = 0; i < 4; ++i) {
    int row = m0 + wm + i * 16 + quad * 4;
#pragma unroll
    for (int j = 0; j < 4; ++j) {
      int col = n0 + wn + j * 16 + l16;
      const float* bp = (col < 1024) ? b0 : (col < 2048 ? b1 : b2);
      float bv = bp ? bp[col & 1023] : 0.f;
#pragma unroll
      for (int r = 0; r < 4; ++r)
        st_out(&C[(size_t)(row + r) * ldc + col], acc[i][j][r] + bv);
    }
  }
}

__global__ __launch_bounds__(256) void gemm_qkv(const bf16_t* __restrict__ A,
                                                const bf16_t* __restrict__ Bt,
                                                bf16_t* __restrict__ C,
                                                const float* bq, const float* bk,
                                                const float* bv) {
  gemm_core<bf16_t>(A, 1024, Bt, 1024, C, 3072, bq, bk, bv, 1024, blockIdx.x, blockIdx.y);
}

__global__ __launch_bounds__(256) void gemm_out(const bf16_t* __restrict__ A,
                                                const bf16_t* __restrict__ Bt,
                                                float* __restrict__ C, const float* bo) {
  gemm_core<float>(A, 1024, Bt, 1024, C, 1024, bo, bo, bo, 1024, blockIdx.x, blockIdx.y);
}

// low = qkv[:, z*1024 : z*1024+1024] @ taT^T  -> lowq/lowk [4096][128]
__global__ __launch_bounds__(256) void gemm_low(const bf16_t* __restrict__ qkv,
                                                const bf16_t* __restrict__ qtaT,
                                                const bf16_t* __restrict__ ktaT,
                                                bf16_t* __restrict__ lowq,
                                                bf16_t* __restrict__ lowk) {
  int z = blockIdx.z;
  gemm_core<bf16_t>(qkv + z * 1024, 3072, z ? ktaT : qtaT, 1024,
                    z ? lowk : lowq, 128, nullptr, nullptr, nullptr, 1024,
                    blockIdx.x, blockIdx.y);
}

// =====================================================================
// fused torsion (both orders): lin_n = Low[:, n*64:(n+1)*64] @ TbT_n^T,
// X += sigmoid(c) * ( sin(2pi l1) l1 + sin(4pi l2) l2 / 2 )
// grid.z: 0 = q (lowq/qtbT/X cols 0:1024), 1 = k
// =====================================================================
__global__ __launch_bounds__(256) void lin_torsion_fused(const bf16_t* __restrict__ lowq,
                                                         const bf16_t* __restrict__ lowk,
                                                         const bf16_t* __restrict__ qtbT,
                                                         const bf16_t* __restrict__ ktbT,
                                                         bf16_t* __restrict__ qkv,
                                                         const float* __restrict__ coupling) {
  __shared__ bf16_t As[128][136];
  __shared__ bf16_t Bs0[128][72];
  __shared__ bf16_t Bs1[128][72];
  const int z = blockIdx.z;
  const bf16_t* Low = z ? lowk : lowq;
  const bf16_t* Tb = z ? ktbT : qtbT;
  bf16_t* X = qkv + z * 1024;

  const int m0 = blockIdx.y * 128, n0 = blockIdx.x * 128;
  const int t = threadIdx.x, w = t >> 6, lane = t & 63;
  const int wm = (w >> 1) * 64, wn = (w & 1) * 64;
  const int quad = lane >> 4, l16 = lane & 15;

  {
    const int sr = t >> 1, sc = (t & 1) * 64;
    const bf16_t* Ag = Low + (size_t)(m0 + sr) * 128 + sc;
#pragma unroll
    for (int i = 0; i < 8; ++i)
      *(float4*)&As[sr][sc + 8 * i] = *(const float4*)(Ag + 8 * i);
    const int br = t >> 1, bc = (t & 1) * 32;
    const bf16_t* Bg0 = Tb + (size_t)(n0 + br) * 64 + bc;
    const bf16_t* Bg1 = Bg0 + 65536;
#pragma unroll
    for (int i = 0; i < 4; ++i) {
      *(float4*)&Bs0[br][bc + 8 * i] = *(const float4*)(Bg0 + 8 * i);
      *(float4*)&Bs1[br][bc + 8 * i] = *(const float4*)(Bg1 + 8 * i);
    }
  }
  __syncthreads();

  f32x4 acc0[4][4] = {}, acc1[4][4] = {};
#pragma unroll
  for (int ks = 0; ks < 2; ++ks) {
    bf16x8 a0[4], a1[4];
#pragma unroll
    for (int i = 0; i < 4; ++i) {
      a0[i] = *(const bf16x8*)&As[wm + i * 16 + l16][ks * 32 + quad * 8];
      a1[i] = *(const bf16x8*)&As[wm + i * 16 + l16][64 + ks * 32 + quad * 8];
    }
#pragma unroll
    for (int j = 0; j < 4; ++j) {
      bf16x8 b0 = *(const bf16x8*)&Bs0[wn + j * 16 + l16][ks * 32 + quad * 8];
      bf16x8 b1 = *(const bf16x8*)&Bs1[wn + j * 16 + l16][ks * 32 + quad * 8];
#pragma unroll
      for (int i = 0; i < 4; ++i) {
        acc0[i][j] = __builtin_amdgcn_mfma_f32_16x16x32_bf16(a0[i], b0, acc0[i][j], 0, 0, 0);
        acc1[i][j] = __builtin_amdgcn_mfma_f32_16x16x32_bf16(a1[i], b1, acc1[i][j], 0, 0, 0);
      }
    }
  }

  const float PI2 = 6.283185307179586f;
  const float sig = 1.f / (1.f + __expf(-coupling[0]));
#pragma unroll
  for (int i = 0; i < 4; ++i) {
#pragma unroll
    for (int j = 0; j < 4; ++j) {
#pragma unroll
      for (int r = 0; r < 4; ++r) {
        int row = m0 + wm + i * 16 + quad * 4 + r;
        int col = n0 + wn + j * 16 + l16;
        size_t idx = (size_t)row * 3072 + col;
        float l1 = acc0[i][j][r], l2 = acc1[i][j][r];
        float corr = sinf(PI2 * l1) * l1 + sinf(2.f * PI2 * l2) * l2 * 0.5f;
        X[idx] = (bf16_t)((float)X[idx] + sig * corr);
      }
    }
  }
}

// =====================================================================
// Flash attention, S^T formulation. B=2, S=2048, NH=16, HD=64.
// qkv packed [4096][3072]. BM=128 (4 waves x 32 queries), BN=128.
// S^T = K·Q^T  ->  C-layout col = query (l16): softmax per-lane-column,
// in-register over 32 keys + 2 cross-quad shuffles. P^T written as b64.
// O^T = V^T·P^T (A = VT fragments, B = P^T fragments, all ds_read_b128).
// 2 barriers/iter. LDS: Ks 18K + VT 17K + Pb 34K = 69K -> 2 blocks/CU.
// =====================================================================
__global__ __launch_bounds__(256) void flash_attn(const bf16_t* __restrict__ qkv,
                                                  bf16_t* __restrict__ Out) {
  constexpr int LD = 3072, SEQ = 2048, LDO = 1024;
  const int qb = blockIdx.x, bh = blockIdx.y;
  const int b = bh >> 4, h = bh & 15;
  const size_t base = (size_t)b * SEQ * LD + h * 64;
  const bf16_t* Qg = qkv + base;
  const bf16_t* Kg = qkv + base + 1024;
  const bf16_t* Vg = qkv + base + 2048;

  __shared__ bf16_t Ks[128][72];   // K tile  [key][ch]
  __shared__ bf16_t VT[64][136];   // V^T     [ch][key]
  __shared__ bf16_t Pb[128][136];  // P       [query][key]; Qs overlays at init

  bf16_t(*Qs)[72] = (bf16_t(*)[72])&Pb[0][0];

  const int t = threadIdx.x, w = t >> 6, lane = t & 63;
  const int quad = lane >> 4, l16 = lane & 15;
  const int sr = t >> 1, scb = (t & 1) * 32;
  const int q0 = qb * 128;
  const float kexp = 0.1803368801111204f;  // (1/8) * log2(e)

  // ---- stage Q, load fragments ----
  {
    const bf16_t* src = Qg + (size_t)(q0 + sr) * LD + scb;
#pragma unroll
    for (int i = 0; i < 4; ++i)
      *(float4*)&Qs[sr][scb + 8 * i] = *(const float4*)(src + 8 * i);
  }
  __syncthreads();
  bf16x8 qf[2][2];
#pragma unroll
  for (int mt = 0; mt < 2; ++mt)
#pragma unroll
    for (int ks = 0; ks < 2; ++ks)
      qf[mt][ks] = *(const bf16x8*)&Qs[w * 32 + mt * 16 + l16][ks * 32 + quad * 8];

  f32x4 o_acc[4][2] = {};
  float m_i[2] = {-1e30f, -1e30f}, l_i[2] = {0.f, 0.f};

  // V-transpose staging indices: thread -> keys g*4..g*4+3, channels cb..cb+7
  const int vg = t >> 3, vcb = (t & 7) * 8;

  for (int k0 = 0; k0 < SEQ; k0 += 128) {
    __syncthreads();  // prev-iter reads of Ks/VT/Pb done (iter0: qf reads done)
    // stage K -> Ks (vector), V -> VT (4-key packed b64 transpose)
    {
      const bf16_t* ksrc = Kg + (size_t)(k0 + sr) * LD + scb;
#pragma unroll
      for (int i = 0; i < 4; ++i)
        *(float4*)&Ks[sr][scb + 8 * i] = *(const float4*)(ksrc + 8 * i);
      const bf16_t* vsrc = Vg + (size_t)(k0 + vg * 4) * LD + vcb;
      union { float4 f; bf16_t h[8]; } vr[4];
#pragma unroll
      for (int kk = 0; kk < 4; ++kk)
        vr[kk].f = *(const float4*)(vsrc + (size_t)kk * LD);
#pragma unroll
      for (int c = 0; c < 8; ++c) {
        union { bf16_t h[4]; uint2 u; } pk;
#pragma unroll
        for (int kk = 0; kk < 4; ++kk) pk.h[kk] = vr[kk].h[c];
        *(uint2*)&VT[vcb + c][vg * 4] = pk.u;
      }
    }
    __syncthreads();  // Ks, VT ready

    // ---- S^T = K · Q^T : tile m=key (j), n=query (w,mt) ----
    f32x4 st[2][8] = {};
#pragma unroll
    for (int ks = 0; ks < 2; ++ks) {
#pragma unroll
      for (int j = 0; j < 8; ++j) {
        bf16x8 kf = *(const bf16x8*)&Ks[j * 16 + l16][ks * 32 + quad * 8];
        st[0][j] = __builtin_amdgcn_mfma_f32_16x16x32_bf16(kf, qf[0][ks], st[0][j], 0, 0, 0);
        st[1][j] = __builtin_amdgcn_mfma_f32_16x16x32_bf16(kf, qf[1][ks], st[1][j], 0, 0, 0);
      }
    }

    // ---- online softmax (per query = per lane column) ----
#pragma unroll
    for (int mt = 0; mt < 2; ++mt) {
      float mx = st[mt][0][0];
#pragma unroll
      for (int j = 0; j < 8; ++j) {
        f32x4 v = st[mt][j];
        mx = fmaxf(mx, fmaxf(fmaxf(v[0], v[1]), fmaxf(v[2], v[3])));
      }
      mx = fmaxf(mx, __shfl_xor(mx, 16));
      mx = fmaxf(mx, __shfl_xor(mx, 32));
      float mnew = fmaxf(m_i[mt], mx);
      float alpha = exp2f((m_i[mt] - mnew) * kexp);
      float negmk = -mnew * kexp;
      m_i[mt] = mnew;
      float rs = 0.f;
#pragma unroll
      for (int j = 0; j < 8; ++j) {
#pragma unroll
        for (int r = 0; r < 4; ++r) {
          float p = exp2f(fmaf(st[mt][j][r], kexp, negmk));
          st[mt][j][r] = p;
          rs += p;
        }
      }
      rs += __shfl_xor(rs, 16);
      rs += __shfl_xor(rs, 32);
      l_i[mt] = l_i[mt] * alpha + rs;
#pragma unroll
      for (int jd = 0; jd < 4; ++jd) {
        o_acc[jd][mt][0] *= alpha; o_acc[jd][mt][1] *= alpha;
        o_acc[jd][mt][2] *= alpha; o_acc[jd][mt][3] *= alpha;
      }
      // P^T -> Pb[query][key], 4 consecutive keys per b64 write (wave-local rows)
#pragma unroll
      for (int j = 0; j < 8; ++j) {
        union { bf16_t h[4]; uint2 u; } pk;
#pragma unroll
        for (int r = 0; r < 4; ++r) pk.h[r] = (bf16_t)st[mt][j][r];
        *(uint2*)&Pb[w * 32 + mt * 16 + l16][j * 16 + quad * 4] = pk.u;
      }
    }

    // ---- O^T += V^T · P^T ----
#pragma unroll
    for (int ks = 0; ks < 4; ++ks) {
      bf16x8 pf0 = *(const bf16x8*)&Pb[w * 32 + l16][ks * 32 + quad * 8];
      bf16x8 pf1 = *(const bf16x8*)&Pb[w * 32 + 16 + l16][ks * 32 + quad * 8];
#pragma unroll
      for (int jd = 0; jd < 4; ++jd) {
        bf16x8 vf = *(const bf16x8*)&VT[jd * 16 + l16][ks * 32 + quad * 8];
        o_acc[jd][0] = __builtin_amdgcn_mfma_f32_16x16x32_bf16(vf, pf0, o_acc[jd][0], 0, 0, 0);
        o_acc[jd][1] = __builtin_amdgcn_mfma_f32_16x16x32_bf16(vf, pf1, o_acc[jd][1], 0, 0, 0);
      }
    }
  }

  // ---- epilogue: O[token][d] = O^T / l, packed 4-col b64 stores ----
#pragma unroll
  for (int mt = 0; mt < 2; ++mt) {
    float inv = 1.f / l_i[mt];
    int token = q0 + w * 32 + mt * 16 + l16;
#pragma unroll
    for (int jd = 0; jd < 4; ++jd) {
      union { bf16_t h[4]; uint2 u; } pk;
#pragma unroll
      for (int r = 0; r < 4; ++r) pk.h[r] = (bf16_t)(o_acc[jd][mt][r] * inv);
      *(uint2*)&Out[(size_t)(b * SEQ + token) * LDO + h * 64 + jd * 16 + quad * 4] = pk.u;
    }
  }
}

// =====================================================================
// host launch
// =====================================================================
extern "C" void kernel_launch(void* const* d_in, const int* in_sizes, int n_in,
                              void* d_out, int out_size, void* d_ws, size_t ws_size,
                              hipStream_t stream) {
  const float* hs   = (const float*)d_in[0];
  const float* Wq   = (const float*)d_in[1];
  const float* bq   = (const float*)d_in[2];
  const float* Wk   = (const float*)d_in[3];
  const float* bk   = (const float*)d_in[4];
  const float* Wv   = (const float*)d_in[5];
  const float* bv   = (const float*)d_in[6];
  const float* Wo   = (const float*)d_in[7];
  const float* bo   = (const float*)d_in[8];
  const float* qta  = (const float*)d_in[9];
  const float* qtb  = (const float*)d_in[10];
  const float* kta  = (const float*)d_in[11];
  const float* ktb  = (const float*)d_in[12];
  const float* coup = (const float*)d_in[13];
  float* out = (float*)d_out;

  uint8_t* ws = (uint8_t*)d_ws;
  bf16_t* hsb   = (bf16_t*)(ws);
  bf16_t* WT    = (bf16_t*)(ws + 8388608);   // [3072][1024]
  bf16_t* WoT   = (bf16_t*)(ws + 14680064);  // [1024][1024]
  bf16_t* qtaT  = (bf16_t*)(ws + 16777216);  // [2][64][1024] transposed
  bf16_t* ktaT  = (bf16_t*)(ws + 17039360);
  bf16_t* qtbT  = (bf16_t*)(ws + 17301504);  // [2][1024][64] transposed
  bf16_t* ktbT  = (bf16_t*)(ws + 17563648);
  bf16_t* qkv   = (bf16_t*)(ws + 17838080);  // [4096][3072]
  bf16_t* lowq  = (bf16_t*)(ws + 43003904);  // [4096][128]
  bf16_t* lowk  = (bf16_t*)(ws + 44052480);
  bf16_t* aout  = (bf16_t*)(ws + 45101056);  // [4096][1024]

  dim3 b256(256);
  dim3 tb(32, 8);

  cvt_f32_bf16<<<2048, b256, 0, stream>>>(hs, hsb, 4194304);
  // Wq->WT[0:1024], Wk->WT[1024:2048], Wv->WT[2048:3072], Wo->WoT
  transpose4<<<dim3(32, 32, 4), tb, 0, stream>>>(Wq, Wk, Wv, Wo,
                                                 WT, WT + 1048576, WT + 2097152, WoT);
  // torsion a: [2][1024][64] -> [2][64][1024]
  transpose_batch<<<dim3(2, 32, 4), tb, 0, stream>>>(qta, kta, qtaT, ktaT, 1024, 64);
  // torsion b: [2][64][1024] -> [2][1024][64]
  transpose_batch<<<dim3(32, 2, 4), tb, 0, stream>>>(qtb, ktb, qtbT, ktbT, 64, 1024);

  // QKV projection with fused bias select
  gemm_qkv<<<dim3(24, 32), b256, 0, stream>>>(hsb, WT, qkv, bq, bk, bv);
  // low-rank projections, q and k fused via grid.z
  gemm_low<<<dim3(1, 32, 2), b256, 0, stream>>>(qkv, qtaT, ktaT, lowq, lowk);
  // fused torsion correction (both orders, q and k via grid.z)
  lin_torsion_fused<<<dim3(8, 32, 2), b256, 0, stream>>>(lowq, lowk, qtbT, ktbT, qkv, coup);
  // attention
  flash_attn<<<dim3(16, 32), b256, 0, stream>>>(qkv, aout);
  // output projection (fp32 out)
  gemm_out<<<dim3(8, 32), b256, 0, stream>>>(aout, WoT, out, bo);
}